// Round 4
// baseline (16790.868 us; speedup 1.0000x reference)
//
#include <hip/hip_runtime.h>
#include <math.h>

#define NSTATES 1024
#define TT      4096
#define DD      20

#define FW_BLOCKS  64
#define FW_THREADS 256
#define JPB  16      // j per block   (FW_BLOCKS * JPB = NSTATES)
#define NSEG 16      // k segments    (seg-fast lane layout: seg = tid&15)
#define KSEG 64      // k per segment (NSEG * KSEG = NSTATES)

#define SENT 0x7FC00000u   // canonical NaN: computed column values are never NaN

// workspace layout (bytes)
#define OFF_LAT   ((size_t)0)               // 4 MB  logA transposed: lat[j*N+k] = log(trans[k][j])
#define OFF_E     ((size_t)4 << 20)         // 16 MB emissions E[t*N+n]
#define OFF_COLS  ((size_t)20 << 20)        // 16 MB per-step columns cols[t*N+j]
#define OFF_PTR   ((size_t)36 << 20)        // 8 MB  u16 backpointers, rows 1..T-1

__global__ void k_init(uint4* __restrict__ cols4) {
    int id = blockIdx.x * 256 + threadIdx.x;
    cols4[id] = make_uint4(SENT, SENT, SENT, SENT);
}

__global__ void k_logtrans(const float* __restrict__ tr, float* __restrict__ lat) {
    int id = blockIdx.x * 256 + threadIdx.x;        // 1M threads
    int k = id >> 10, j = id & 1023;
    lat[(size_t)j * NSTATES + k] = logf(tr[id]);
}

__global__ void k_emis(const float* __restrict__ ev, const float* __restrict__ epar,
                       const float* __restrict__ prior, float* __restrict__ E,
                       float* __restrict__ cols) {
    int n = blockIdx.x * 256 + threadIdx.x;         // 4 x 256 = 1024
    int t = blockIdx.y;                             // 0..4095
    const float* ep = epar + (size_t)n * (2 * DD);
    const float* x  = ev + (size_t)t * DD;
    float acc = 0.0f;
    #pragma unroll
    for (int d = 0; d < DD; ++d) {
        float m = ep[2 * d];
        float s = ep[2 * d + 1];
        float tp   = 6.2831853071795864769f * s;
        float coef = 1.0f / sqrtf(tp);
        float df   = x[d] - m;
        float num  = df * df;
        float den  = 2.0f * (s * s);
        float p    = coef * expf(-num / den);
        acc += logf(p);                             // -inf propagates; never NaN
    }
    E[(size_t)t * NSTATES + n] = acc;
    if (t == 0) cols[n] = logf(prior[n]) + acc;     // col0 overwrites sentinel
}

__global__ __launch_bounds__(FW_THREADS, 1) void k_forward(
    const float* __restrict__ lat, const float* __restrict__ E,
    float* __restrict__ cols, unsigned short* __restrict__ bptr)
{
    __shared__ float prevs[NSTATES];
    const int tid = threadIdx.x;
    const int seg = tid & (NSEG - 1);                // fast index -> intra-wave reduce
    const int jj  = tid >> 4;                        // 0..15
    const int j   = blockIdx.x * JPB + jj;
    const int kbase4 = seg * (KSEG / 4);             // float4 base: seg*16 float4 = seg*64 floats

    // loop-invariant: this lane's 64 lat values -> 16 float4 registers
    const float* lrow = lat + (size_t)j * NSTATES + seg * KSEG;
    float4 latreg[16];
    #pragma unroll
    for (int u = 0; u < 16; ++u) latreg[u] = *(const float4*)(lrow + 4 * u);
    const float lat00 = lat[0];                      // log trans[0][0], j==0 quirk

    for (int t = 1; t < TT; ++t) {
        // issue E early: latency hides behind poll + compute
        const float ej = E[(size_t)t * NSTATES + j];

        // poll previous column: data-as-flag, relaxed sc1 loads (no L2 invalidate)
        const unsigned* p = (const unsigned*)(cols + (size_t)(t - 1) * NSTATES) + tid * 4;
        unsigned w0, w1, w2, w3;
        for (;;) {
            w0 = __hip_atomic_load(p + 0, __ATOMIC_RELAXED, __HIP_MEMORY_SCOPE_AGENT);
            w1 = __hip_atomic_load(p + 1, __ATOMIC_RELAXED, __HIP_MEMORY_SCOPE_AGENT);
            w2 = __hip_atomic_load(p + 2, __ATOMIC_RELAXED, __HIP_MEMORY_SCOPE_AGENT);
            w3 = __hip_atomic_load(p + 3, __ATOMIC_RELAXED, __HIP_MEMORY_SCOPE_AGENT);
            if (w0 != SENT && w1 != SENT && w2 != SENT && w3 != SENT) break;
        }
        prevs[tid * 4 + 0] = __uint_as_float(w0);
        prevs[tid * 4 + 1] = __uint_as_float(w1);
        prevs[tid * 4 + 2] = __uint_as_float(w2);
        prevs[tid * 4 + 3] = __uint_as_float(w3);
        __syncthreads();

        // per-lane scan of its 64-k segment: first-max (strict >, ascending k)
        float best = -__builtin_inff();
        int bidx = seg * KSEG;
        #pragma unroll
        for (int u = 0; u < 16; ++u) {
            float4 q = *(const float4*)(prevs + (kbase4 + u) * 4);   // floats seg*64 + 4u
            int k0 = seg * KSEG + u * 4;
            float v0 = q.x + latreg[u].x;
            float v1 = q.y + latreg[u].y;
            float v2 = q.z + latreg[u].z;
            float v3 = q.w + latreg[u].w;
            if (v0 > best) { best = v0; bidx = k0;     }
            if (v1 > best) { best = v1; bidx = k0 + 1; }
            if (v2 > best) { best = v2; bidx = k0 + 2; }
            if (v3 > best) { best = v3; bidx = k0 + 3; }
        }
        // combine 16 segment partials (lanes seg=0..15 of this jj) via butterfly;
        // min-index tie-break == global first-max over ascending k
        #pragma unroll
        for (int off = 1; off < NSEG; off <<= 1) {
            float ov = __shfl_xor(best, off);
            int   oi = __shfl_xor(bidx, off);
            if (ov > best || (ov == best && oi < bidx)) { best = ov; bidx = oi; }
        }

        if (seg == 0) {
            // reference quirk: j==0 value forced from state 0 (ptr keeps true argmax)
            float val = (j == 0) ? (prevs[0] + lat00) : best;
            float out = val + ej;
            __hip_atomic_store((unsigned*)(cols + (size_t)t * NSTATES) + j,
                               __float_as_uint(out), __ATOMIC_RELAXED,
                               __HIP_MEMORY_SCOPE_AGENT);
            bptr[(size_t)t * NSTATES + j] = (unsigned short)bidx;
        }
        __syncthreads();   // protect prevs before next iteration's overwrite
    }
}

#define BT_THREADS 256
#define BTC 15   // rows per LDS chunk; 2 buffers * 15 * 2KB = 60 KB (< 64 KB static LDS)
__global__ __launch_bounds__(BT_THREADS, 1) void k_backtrace(
    const float* __restrict__ lastcol,
    const unsigned short* __restrict__ bptr,
    int* __restrict__ seq)
{
    __shared__ unsigned short ring[2][BTC][NSTATES];
    __shared__ int s_front;
    const int tid = threadIdx.x;

    if (tid < 64) {
        // last = first-max argmax over final column (wave 0 only)
        float best = -__builtin_inff();
        int bi = 0;
        for (int n2 = tid; n2 < NSTATES; n2 += 64) {
            float v = lastcol[n2];
            if (v > best) { best = v; bi = n2; }
        }
        #pragma unroll
        for (int off = 32; off > 0; off >>= 1) {
            float ov = __shfl_xor(best, off);
            int   oi = __shfl_xor(bi, off);
            if (ov > best || (ov == best && oi < bi)) { best = ov; bi = oi; }
        }
        if (tid == 0) { seq[TT] = bi; seq[TT - 1] = bi; s_front = bi; }
    }

    // stage first chunk (rows rhi-BTC+1 .. rhi), all threads
    int rhi = TT - 1;
    {
        int rlo = rhi - BTC + 1; if (rlo < 1) rlo = 1;
        int nq = (rhi - rlo + 1) * 128;              // uint4 (8 u16) per row = 128
        for (int idx = tid; idx < nq; idx += BT_THREADS) {
            int row = idx >> 7, q = idx & 127;
            ((uint4*)&ring[0][row][0])[q] =
                ((const uint4*)(bptr + (size_t)(rlo + row) * NSTATES))[q];
        }
    }
    __syncthreads();

    int buf = 0;
    while (rhi >= 1) {
        int rlo = rhi - BTC + 1; if (rlo < 1) rlo = 1;
        int nrhi = rlo - 1;
        if (tid == 0) {
            // chase current chunk
            int front = s_front;
            for (int r = rhi; r >= rlo; --r) {
                front = (int)ring[buf][r - rlo][front];
                seq[r - 1] = front;
            }
            s_front = front;
        } else if (nrhi >= 1) {
            // overlap: stage next chunk with the other 255 threads
            int nrlo = nrhi - BTC + 1; if (nrlo < 1) nrlo = 1;
            int nq = (nrhi - nrlo + 1) * 128;
            for (int idx = tid - 1; idx < nq; idx += (BT_THREADS - 1)) {
                int row = idx >> 7, q = idx & 127;
                ((uint4*)&ring[buf ^ 1][row][0])[q] =
                    ((const uint4*)(bptr + (size_t)(nrlo + row) * NSTATES))[q];
            }
        }
        __syncthreads();
        buf ^= 1;
        rhi = nrhi;
    }
}

extern "C" void kernel_launch(void* const* d_in, const int* in_sizes, int n_in,
                              void* d_out, int out_size, void* d_ws, size_t ws_size,
                              hipStream_t stream) {
    const float* ev    = (const float*)d_in[0];   // [T, D]
    const float* prior = (const float*)d_in[1];   // [N]
    const float* tr    = (const float*)d_in[2];   // [N, N]
    const float* epar  = (const float*)d_in[3];   // [N, D, 2]
    int* seq = (int*)d_out;                       // [T+1]
    char* ws = (char*)d_ws;
    float* lat  = (float*)(ws + OFF_LAT);
    float* E    = (float*)(ws + OFF_E);
    float* cols = (float*)(ws + OFF_COLS);
    unsigned short* bptr = (unsigned short*)(ws + OFF_PTR);

    k_init<<<4096, 256, 0, stream>>>((uint4*)cols);              // sentinel-fill 16 MB
    k_logtrans<<<4096, 256, 0, stream>>>(tr, lat);
    k_emis<<<dim3(4, TT), 256, 0, stream>>>(ev, epar, prior, E, cols);
    k_forward<<<FW_BLOCKS, FW_THREADS, 0, stream>>>(lat, E, cols, bptr);
    k_backtrace<<<1, BT_THREADS, 0, stream>>>(cols + (size_t)(TT - 1) * NSTATES, bptr, seq);
}

// Round 5
// 15246.143 us; speedup vs baseline: 1.1013x; 1.1013x over previous
//
#include <hip/hip_runtime.h>
#include <math.h>

#define NSTATES 1024
#define TT      4096
#define DD      20

#define FW_BLOCKS  64
#define FW_THREADS 256
#define JPB  16      // j per block   (FW_BLOCKS * JPB = NSTATES)
#define NSEG 16      // k segments    (seg-fast lane layout: seg = tid&15)
#define KSEG 64      // k per segment (NSEG * KSEG = NSTATES)

#define SENT 0x7FC00000u   // canonical NaN: computed column values are never NaN

// workspace layout (bytes)
#define OFF_LAT   ((size_t)0)               // 4 MB  logA transposed: lat[j*N+k] = log(trans[k][j])
#define OFF_E     ((size_t)4 << 20)         // 16 MB emissions E[t*N+n]
#define OFF_COLS  ((size_t)20 << 20)        // 16 MB per-step columns cols[t*N+j]
#define OFF_PTR   ((size_t)36 << 20)        // 8 MB  u16 backpointers, rows 1..T-1

// XOR-swizzle for prevs LDS storage (float4 granularity):
// logical f -> phys (f & ~15) | ((f & 15) ^ (f >> 4))   [f in 0..255, f>>4 in 0..15]
__device__ __forceinline__ int swz(int f) {
    return (f & ~15) | ((f & 15) ^ (f >> 4));
}

__global__ void k_init(uint4* __restrict__ cols4) {
    int id = blockIdx.x * 256 + threadIdx.x;
    cols4[id] = make_uint4(SENT, SENT, SENT, SENT);
}

__global__ void k_logtrans(const float* __restrict__ tr, float* __restrict__ lat) {
    int id = blockIdx.x * 256 + threadIdx.x;        // 1M threads
    int k = id >> 10, j = id & 1023;
    lat[(size_t)j * NSTATES + k] = logf(tr[id]);
}

__global__ void k_emis(const float* __restrict__ ev, const float* __restrict__ epar,
                       const float* __restrict__ prior, float* __restrict__ E,
                       float* __restrict__ cols) {
    int n = blockIdx.x * 256 + threadIdx.x;         // 4 x 256 = 1024
    int t = blockIdx.y;                             // 0..4095
    const float* ep = epar + (size_t)n * (2 * DD);
    const float* x  = ev + (size_t)t * DD;
    float acc = 0.0f;
    #pragma unroll
    for (int d = 0; d < DD; ++d) {
        float m = ep[2 * d];
        float s = ep[2 * d + 1];
        float tp   = 6.2831853071795864769f * s;
        float coef = 1.0f / sqrtf(tp);
        float df   = x[d] - m;
        float num  = df * df;
        float den  = 2.0f * (s * s);
        float p    = coef * expf(-num / den);
        acc += logf(p);                             // -inf propagates; never NaN
    }
    E[(size_t)t * NSTATES + n] = acc;
    if (t == 0) cols[n] = logf(prior[n]) + acc;     // col0 overwrites sentinel
}

__global__ __launch_bounds__(FW_THREADS, 1) void k_forward(
    const float* __restrict__ lat, const float* __restrict__ E,
    float* __restrict__ cols, unsigned short* __restrict__ bptr)
{
    __shared__ float prevs[NSTATES];                 // stored XOR-swizzled (float4 granularity)
    const int tid = threadIdx.x;
    const int seg = tid & (NSEG - 1);                // fast index -> intra-wave reduce
    const int jj  = tid >> 4;                        // 0..15
    const int j   = blockIdx.x * JPB + jj;
    const int wphys = swz(tid);                      // phys float4 slot this thread writes

    // loop-invariant: this lane's 64 lat values -> 16 float4 registers
    const float* lrow = lat + (size_t)j * NSTATES + seg * KSEG;
    float4 latreg[16];
    #pragma unroll
    for (int u = 0; u < 16; ++u) latreg[u] = *(const float4*)(lrow + 4 * u);
    // pin latreg in VGPRs: stop the compiler sinking these loads into the t-loop
    #pragma unroll
    for (int u = 0; u < 16; ++u) {
        asm volatile("" : "+v"(latreg[u].x), "+v"(latreg[u].y),
                          "+v"(latreg[u].z), "+v"(latreg[u].w));
    }
    const float lat00 = lat[0];                      // log trans[0][0], j==0 quirk

    for (int t = 1; t < TT; ++t) {
        // issue E early: latency hides behind poll + compute
        const float ej = E[(size_t)t * NSTATES + j];

        // poll previous column: data-as-flag, relaxed sc1 loads (no L2 invalidate)
        const unsigned* p = (const unsigned*)(cols + (size_t)(t - 1) * NSTATES) + tid * 4;
        unsigned w0, w1, w2, w3;
        for (;;) {
            w0 = __hip_atomic_load(p + 0, __ATOMIC_RELAXED, __HIP_MEMORY_SCOPE_AGENT);
            w1 = __hip_atomic_load(p + 1, __ATOMIC_RELAXED, __HIP_MEMORY_SCOPE_AGENT);
            w2 = __hip_atomic_load(p + 2, __ATOMIC_RELAXED, __HIP_MEMORY_SCOPE_AGENT);
            w3 = __hip_atomic_load(p + 3, __ATOMIC_RELAXED, __HIP_MEMORY_SCOPE_AGENT);
            if (w0 != SENT && w1 != SENT && w2 != SENT && w3 != SENT) break;
        }
        ((uint4*)prevs)[wphys] = make_uint4(w0, w1, w2, w3);   // swizzled store
        __syncthreads();

        // per-lane scan of its 64-k segment: first-max (strict >, ascending k).
        // swizzled read: logical f = seg*16+u  ->  phys seg*16 + (u^seg); 2-way banks = free
        float best = -__builtin_inff();
        int bidx = seg * KSEG;
        #pragma unroll
        for (int u = 0; u < 16; ++u) {
            float4 q = ((const float4*)prevs)[seg * 16 + (u ^ seg)];
            int k0 = seg * KSEG + u * 4;
            float v0 = q.x + latreg[u].x;
            float v1 = q.y + latreg[u].y;
            float v2 = q.z + latreg[u].z;
            float v3 = q.w + latreg[u].w;
            if (v0 > best) { best = v0; bidx = k0;     }
            if (v1 > best) { best = v1; bidx = k0 + 1; }
            if (v2 > best) { best = v2; bidx = k0 + 2; }
            if (v3 > best) { best = v3; bidx = k0 + 3; }
        }
        // combine 16 segment partials (lanes seg=0..15 of this jj) via butterfly;
        // min-index tie-break == global first-max over ascending k
        #pragma unroll
        for (int off = 1; off < NSEG; off <<= 1) {
            float ov = __shfl_xor(best, off);
            int   oi = __shfl_xor(bidx, off);
            if (ov > best || (ov == best && oi < bidx)) { best = ov; bidx = oi; }
        }

        if (seg == 0) {
            // reference quirk: j==0 value forced from state 0 (ptr keeps true argmax);
            // prevs logical float 0 lives at phys float 0 (swz(0)==0)
            float val = (j == 0) ? (prevs[0] + lat00) : best;
            float out = val + ej;
            __hip_atomic_store((unsigned*)(cols + (size_t)t * NSTATES) + j,
                               __float_as_uint(out), __ATOMIC_RELAXED,
                               __HIP_MEMORY_SCOPE_AGENT);
            bptr[(size_t)t * NSTATES + j] = (unsigned short)bidx;
        }
        __syncthreads();   // protect prevs before next iteration's overwrite
    }
}

#define BT_THREADS 256
#define BTC 15   // rows per LDS chunk; 2 buffers * 15 * 2KB = 60 KB (< 64 KB static LDS)
__global__ __launch_bounds__(BT_THREADS, 1) void k_backtrace(
    const float* __restrict__ lastcol,
    const unsigned short* __restrict__ bptr,
    int* __restrict__ seq)
{
    __shared__ unsigned short ring[2][BTC][NSTATES];
    __shared__ int s_front;
    const int tid = threadIdx.x;

    if (tid < 64) {
        // last = first-max argmax over final column (wave 0 only)
        float best = -__builtin_inff();
        int bi = 0;
        for (int n2 = tid; n2 < NSTATES; n2 += 64) {
            float v = lastcol[n2];
            if (v > best) { best = v; bi = n2; }
        }
        #pragma unroll
        for (int off = 32; off > 0; off >>= 1) {
            float ov = __shfl_xor(best, off);
            int   oi = __shfl_xor(bi, off);
            if (ov > best || (ov == best && oi < bi)) { best = ov; bi = oi; }
        }
        if (tid == 0) { seq[TT] = bi; seq[TT - 1] = bi; s_front = bi; }
    }

    // stage first chunk (rows rhi-BTC+1 .. rhi), all threads
    int rhi = TT - 1;
    {
        int rlo = rhi - BTC + 1; if (rlo < 1) rlo = 1;
        int nq = (rhi - rlo + 1) * 128;              // uint4 (8 u16) per row = 128
        for (int idx = tid; idx < nq; idx += BT_THREADS) {
            int row = idx >> 7, q = idx & 127;
            ((uint4*)&ring[0][row][0])[q] =
                ((const uint4*)(bptr + (size_t)(rlo + row) * NSTATES))[q];
        }
    }
    __syncthreads();

    int buf = 0;
    while (rhi >= 1) {
        int rlo = rhi - BTC + 1; if (rlo < 1) rlo = 1;
        int nrhi = rlo - 1;
        if (tid == 0) {
            // chase current chunk
            int front = s_front;
            for (int r = rhi; r >= rlo; --r) {
                front = (int)ring[buf][r - rlo][front];
                seq[r - 1] = front;
            }
            s_front = front;
        } else if (nrhi >= 1) {
            // overlap: stage next chunk with the other 255 threads
            int nrlo = nrhi - BTC + 1; if (nrlo < 1) nrlo = 1;
            int nq = (nrhi - nrlo + 1) * 128;
            for (int idx = tid - 1; idx < nq; idx += (BT_THREADS - 1)) {
                int row = idx >> 7, q = idx & 127;
                ((uint4*)&ring[buf ^ 1][row][0])[q] =
                    ((const uint4*)(bptr + (size_t)(nrlo + row) * NSTATES))[q];
            }
        }
        __syncthreads();
        buf ^= 1;
        rhi = nrhi;
    }
}

extern "C" void kernel_launch(void* const* d_in, const int* in_sizes, int n_in,
                              void* d_out, int out_size, void* d_ws, size_t ws_size,
                              hipStream_t stream) {
    const float* ev    = (const float*)d_in[0];   // [T, D]
    const float* prior = (const float*)d_in[1];   // [N]
    const float* tr    = (const float*)d_in[2];   // [N, N]
    const float* epar  = (const float*)d_in[3];   // [N, D, 2]
    int* seq = (int*)d_out;                       // [T+1]
    char* ws = (char*)d_ws;
    float* lat  = (float*)(ws + OFF_LAT);
    float* E    = (float*)(ws + OFF_E);
    float* cols = (float*)(ws + OFF_COLS);
    unsigned short* bptr = (unsigned short*)(ws + OFF_PTR);

    k_init<<<4096, 256, 0, stream>>>((uint4*)cols);              // sentinel-fill 16 MB
    k_logtrans<<<4096, 256, 0, stream>>>(tr, lat);
    k_emis<<<dim3(4, TT), 256, 0, stream>>>(ev, epar, prior, E, cols);
    k_forward<<<FW_BLOCKS, FW_THREADS, 0, stream>>>(lat, E, cols, bptr);
    k_backtrace<<<1, BT_THREADS, 0, stream>>>(cols + (size_t)(TT - 1) * NSTATES, bptr, seq);
}

// Round 6
// 13086.037 us; speedup vs baseline: 1.2831x; 1.1651x over previous
//
#include <hip/hip_runtime.h>
#include <math.h>

#define NSTATES 1024
#define TT      4096
#define DD      20

#define FW_BLOCKS  64
#define FW_THREADS 256
#define JPB  16      // j per block   (FW_BLOCKS * JPB = NSTATES)
#define NSEG 16      // k segments    (seg-fast lane layout: seg = tid&15)
#define KSEG 64      // k per segment (NSEG * KSEG = NSTATES)

#define SENT 0x7FC00000u   // canonical NaN: computed column values are never NaN

// workspace layout (bytes)
#define OFF_LAT   ((size_t)0)               // 4 MB  logA transposed: lat[j*N+k] = log(trans[k][j])
#define OFF_E     ((size_t)4 << 20)         // 16 MB emissions E[t*N+n]
#define OFF_COLS  ((size_t)20 << 20)        // 16 MB per-step columns cols[t*N+j]
#define OFF_PTR   ((size_t)36 << 20)        // 8 MB  u16 backpointers, rows 1..T-1

// XOR-swizzle for prevs LDS storage (float4 granularity, f in 0..255):
// logical f -> phys (f & ~15) | ((f & 15) ^ (f >> 4))
__device__ __forceinline__ int swz(int f) {
    return (f & ~15) | ((f & 15) ^ (f >> 4));
}

__global__ void k_init(uint4* __restrict__ cols4) {
    int id = blockIdx.x * 256 + threadIdx.x;
    cols4[id] = make_uint4(SENT, SENT, SENT, SENT);
}

__global__ void k_logtrans(const float* __restrict__ tr, float* __restrict__ lat) {
    int id = blockIdx.x * 256 + threadIdx.x;        // 1M threads
    int k = id >> 10, j = id & 1023;
    lat[(size_t)j * NSTATES + k] = logf(tr[id]);
}

__global__ void k_emis(const float* __restrict__ ev, const float* __restrict__ epar,
                       const float* __restrict__ prior, float* __restrict__ E,
                       float* __restrict__ cols) {
    int n = blockIdx.x * 256 + threadIdx.x;         // 4 x 256 = 1024
    int t = blockIdx.y;                             // 0..4095
    const float* ep = epar + (size_t)n * (2 * DD);
    const float* x  = ev + (size_t)t * DD;
    float acc = 0.0f;
    #pragma unroll
    for (int d = 0; d < DD; ++d) {
        float m = ep[2 * d];
        float s = ep[2 * d + 1];
        float tp   = 6.2831853071795864769f * s;
        float coef = 1.0f / sqrtf(tp);
        float df   = x[d] - m;
        float num  = df * df;
        float den  = 2.0f * (s * s);
        float p    = coef * expf(-num / den);
        acc += logf(p);                             // -inf propagates; never NaN
    }
    E[(size_t)t * NSTATES + n] = acc;
    if (t == 0) cols[n] = logf(prior[n]) + acc;     // col0 overwrites sentinel
}

__device__ __forceinline__ bool ok64(unsigned long long q) {
    return ((unsigned)q != SENT) && ((unsigned)(q >> 32) != SENT);
}

__global__ __launch_bounds__(FW_THREADS, 1) void k_forward(
    const float* __restrict__ lat, const float* __restrict__ E,
    float* __restrict__ cols, unsigned short* __restrict__ bptr)
{
    __shared__ float prevs[2][NSTATES];              // double-buffered, XOR-swizzled (float4)
    __shared__ float eBuf[2][64][JPB];               // E staged in 64-step chunks, dbuf
    const int tid = threadIdx.x;
    const int seg = tid & (NSEG - 1);                // fast index -> intra-wave reduce
    const int jj  = tid >> 4;                        // 0..15
    const int j0  = blockIdx.x * JPB;
    const int j   = j0 + jj;
    const int wphys = swz(tid);                      // phys float4 slot this thread writes
    const float* lrow = lat + (size_t)j * NSTATES + seg * KSEG;
    const float lat00 = lat[0];                      // log trans[0][0], j==0 quirk

    for (int t = 1; t < TT; ++t) {
        const int pb    = t & 1;
        const int ebsel = ((t - 1) >> 6) & 1;

        // ---- poll previous column: u64 relaxed agent loads + s_sleep backoff ----
        const unsigned long long* pc =
            (const unsigned long long*)cols + (size_t)(t - 1) * (NSTATES / 2) + tid * 2;
        unsigned long long q0, q1;
        for (;;) {
            q0 = __hip_atomic_load(pc + 0, __ATOMIC_RELAXED, __HIP_MEMORY_SCOPE_AGENT);
            q1 = __hip_atomic_load(pc + 1, __ATOMIC_RELAXED, __HIP_MEMORY_SCOPE_AGENT);
            if (ok64(q0) && ok64(q1)) break;
            __builtin_amdgcn_s_sleep(1);
        }
        ((uint4*)prevs[pb])[wphys] =
            make_uint4((unsigned)q0, (unsigned)(q0 >> 32),
                       (unsigned)q1, (unsigned)(q1 >> 32));   // swizzled store

        // ---- stage E rows t..t+63 into LDS once per 64 steps (off critical path) ----
        if (((t - 1) & 63) == 0) {
            for (int i = tid; i < 64 * JPB; i += FW_THREADS) {
                int r = i >> 4, c = i & 15;
                int row = t + r;
                float v = (row < TT) ? E[(size_t)row * NSTATES + j0 + c] : 0.0f;
                eBuf[ebsel][r][c] = v;
            }
        }
        __syncthreads();

        // ---- per-lane scan of its 64-k segment: first-max (strict >, ascending k) ----
        // lat streams from L2 (64 B/lane/step); prevs from swizzled LDS (2-way = free)
        float best = -__builtin_inff();
        int bidx = seg * KSEG;
        #pragma unroll
        for (int u = 0; u < 16; ++u) {
            float4 w = *(const float4*)(lrow + 4 * u);
            float4 q = ((const float4*)prevs[pb])[seg * 16 + (u ^ seg)];
            int k0 = seg * KSEG + u * 4;
            float v0 = q.x + w.x;
            float v1 = q.y + w.y;
            float v2 = q.z + w.z;
            float v3 = q.w + w.w;
            if (v0 > best) { best = v0; bidx = k0;     }
            if (v1 > best) { best = v1; bidx = k0 + 1; }
            if (v2 > best) { best = v2; bidx = k0 + 2; }
            if (v3 > best) { best = v3; bidx = k0 + 3; }
        }
        // combine 16 partials (lanes seg=0..15 of this jj) via butterfly;
        // min-index tie-break == global first-max; result lands in ALL 16 lanes
        #pragma unroll
        for (int off = 1; off < NSEG; off <<= 1) {
            float ov = __shfl_xor(best, off);
            int   oi = __shfl_xor(bidx, off);
            if (ov > best || (ov == best && oi < bidx)) { best = ov; bidx = oi; }
        }

        // reference quirk: j==0 value forced from state 0 (ptr keeps true argmax);
        // prevs logical float 0 is at phys float 0 (swz(0)==0)
        float ej  = eBuf[ebsel][(t - 1) & 63][jj];
        float val = (j == 0) ? (prevs[pb][0] + lat00) : best;
        float out = val + ej;

        // ---- publish: pack (j, j+1) into one u64 relaxed agent store ----
        float vhi = __shfl(out, tid + 16);           // jj+1's result (uniform shfl)
        if ((tid & 31) == 0) {                       // seg==0, even jj
            unsigned long long packed =
                (unsigned long long)__float_as_uint(out) |
                ((unsigned long long)__float_as_uint(vhi) << 32);
            __hip_atomic_store((unsigned long long*)cols +
                                   (size_t)t * (NSTATES / 2) + (j >> 1),
                               packed, __ATOMIC_RELAXED, __HIP_MEMORY_SCOPE_AGENT);
        }
        if (seg == 0) {
            bptr[(size_t)t * NSTATES + j] = (unsigned short)bidx;   // after publish
        }
        // no trailing barrier: next iteration writes the other prevs/eBuf buffer
    }
}

#define BT_THREADS 256
#define BTC 15   // rows per LDS chunk; 2 buffers * 15 * 2KB = 60 KB (< 64 KB static LDS)
__global__ __launch_bounds__(BT_THREADS, 1) void k_backtrace(
    const float* __restrict__ lastcol,
    const unsigned short* __restrict__ bptr,
    int* __restrict__ seq)
{
    __shared__ unsigned short ring[2][BTC][NSTATES];
    __shared__ int s_front;
    const int tid = threadIdx.x;

    if (tid < 64) {
        // last = first-max argmax over final column (wave 0 only)
        float best = -__builtin_inff();
        int bi = 0;
        for (int n2 = tid; n2 < NSTATES; n2 += 64) {
            float v = lastcol[n2];
            if (v > best) { best = v; bi = n2; }
        }
        #pragma unroll
        for (int off = 32; off > 0; off >>= 1) {
            float ov = __shfl_xor(best, off);
            int   oi = __shfl_xor(bi, off);
            if (ov > best || (ov == best && oi < bi)) { best = ov; bi = oi; }
        }
        if (tid == 0) { seq[TT] = bi; seq[TT - 1] = bi; s_front = bi; }
    }

    // stage first chunk (rows rhi-BTC+1 .. rhi), all threads
    int rhi = TT - 1;
    {
        int rlo = rhi - BTC + 1; if (rlo < 1) rlo = 1;
        int nq = (rhi - rlo + 1) * 128;              // uint4 (8 u16) per row = 128
        for (int idx = tid; idx < nq; idx += BT_THREADS) {
            int row = idx >> 7, q = idx & 127;
            ((uint4*)&ring[0][row][0])[q] =
                ((const uint4*)(bptr + (size_t)(rlo + row) * NSTATES))[q];
        }
    }
    __syncthreads();

    int buf = 0;
    while (rhi >= 1) {
        int rlo = rhi - BTC + 1; if (rlo < 1) rlo = 1;
        int nrhi = rlo - 1;
        if (tid == 0) {
            // chase current chunk
            int front = s_front;
            for (int r = rhi; r >= rlo; --r) {
                front = (int)ring[buf][r - rlo][front];
                seq[r - 1] = front;
            }
            s_front = front;
        } else if (nrhi >= 1) {
            // overlap: stage next chunk with the other 255 threads
            int nrlo = nrhi - BTC + 1; if (nrlo < 1) nrlo = 1;
            int nq = (nrhi - nrlo + 1) * 128;
            for (int idx = tid - 1; idx < nq; idx += (BT_THREADS - 1)) {
                int row = idx >> 7, q = idx & 127;
                ((uint4*)&ring[buf ^ 1][row][0])[q] =
                    ((const uint4*)(bptr + (size_t)(nrlo + row) * NSTATES))[q];
            }
        }
        __syncthreads();
        buf ^= 1;
        rhi = nrhi;
    }
}

extern "C" void kernel_launch(void* const* d_in, const int* in_sizes, int n_in,
                              void* d_out, int out_size, void* d_ws, size_t ws_size,
                              hipStream_t stream) {
    const float* ev    = (const float*)d_in[0];   // [T, D]
    const float* prior = (const float*)d_in[1];   // [N]
    const float* tr    = (const float*)d_in[2];   // [N, N]
    const float* epar  = (const float*)d_in[3];   // [N, D, 2]
    int* seq = (int*)d_out;                       // [T+1]
    char* ws = (char*)d_ws;
    float* lat  = (float*)(ws + OFF_LAT);
    float* E    = (float*)(ws + OFF_E);
    float* cols = (float*)(ws + OFF_COLS);
    unsigned short* bptr = (unsigned short*)(ws + OFF_PTR);

    k_init<<<4096, 256, 0, stream>>>((uint4*)cols);              // sentinel-fill 16 MB
    k_logtrans<<<4096, 256, 0, stream>>>(tr, lat);
    k_emis<<<dim3(4, TT), 256, 0, stream>>>(ev, epar, prior, E, cols);
    k_forward<<<FW_BLOCKS, FW_THREADS, 0, stream>>>(lat, E, cols, bptr);
    k_backtrace<<<1, BT_THREADS, 0, stream>>>(cols + (size_t)(TT - 1) * NSTATES, bptr, seq);
}